// Round 1
// baseline (166.017 us; speedup 1.0000x reference)
//
#include <hip/hip_runtime.h>
#include <stdint.h>

// ---------------- problem constants ----------------
#define NIMG   64
#define NCH    2048
#define HW7    49          // 7*7
#define OUTW   224
#define NPIX   50176       // 224*224
#define CROP_N 9633792     // 64*3*224*224
#define HEAT_OFF  9633792
#define COORD_OFF 12845056 // CROP_N + 64*NPIX
#define THRESH 0.7f

#define MAXR 8             // max runs kept per row (theoretical max is 4)
#define RCAP (224*MAXR)    // 1792 run slots per image
#define NWORDS 784         // 50176 bits / 64
#define WPAD   788         // padded so row extraction can read +4 words

// scratch layout inside d_out's crop region (overwritten by k5 afterwards):
//   byte 0      : unsigned heatBins[64*49]           (12544 B)
//   byte 16384  : unsigned long long maskW[64*788]   (403456 B) -> ends 419840
#define SCRATCH_ULL 52480  // 419840/8

// =====================================================================
// K0: zero the scratch area (d_out is poisoned 0xAA before every launch)
// =====================================================================
__global__ __launch_bounds__(256) void k0_zero(unsigned long long* base) {
    int id = blockIdx.x * 256 + threadIdx.x;
    if (id < SCRATCH_ULL) base[id] = 0ull;
}

// =====================================================================
// K1: heat[n][pos] = max_c |features[n][c][pos]|  (as uint bits; all >=0
// so uint compare == float compare). 512 blocks = 8 chunks x 64 images.
// =====================================================================
__global__ __launch_bounds__(256) void k1_heat(const float* __restrict__ F,
                                               unsigned* __restrict__ heatBins) {
    __shared__ unsigned hU[HW7];
    const int t = threadIdx.x;
    const int b = blockIdx.x;
    const int n = b >> 3, chunk = b & 7;
    if (t < HW7) hU[t] = 0u;
    __syncthreads();
    // elements for this block: f = chunk*12544 + t + 256*r, r in [0,49)
    // image-flat pos = f % 49 = (t + 11*r) % 49   (12544 = 256*49)
    const float* Fp = F + (size_t)n * 100352 + (size_t)chunk * 12544 + t;
    int pos = t % 49;
#pragma unroll
    for (int r = 0; r < 49; ++r) {
        float v = fabsf(Fp[r * 256]);
        atomicMax(&hU[pos], __float_as_uint(v));
        pos += 11; if (pos >= 49) pos -= 49;
    }
    __syncthreads();
    if (t < HW7) atomicMax(&heatBins[n * HW7 + t], hU[t]);
}

// =====================================================================
// K2: normalize heat, bilinear upsample to 224x224 (output), build mask
// bit-words via ballot. 512 blocks = 8 row-slices x 64 images.
// =====================================================================
__device__ inline float bilin7(const float* h7, int i, int j) {
#pragma clang fp contract(off)
    float gx = (float)i / 223.0f;
    float gy = (float)j / 223.0f;
    float xs = gx * 6.0f;
    float ys = gy * 6.0f;
    int x0 = (int)floorf(xs); x0 = min(max(x0, 0), 6); int x1 = min(x0 + 1, 6);
    int y0 = (int)floorf(ys); y0 = min(max(y0, 0), 6); int y1 = min(y0 + 1, 6);
    float wx = xs - (float)x0;
    float wy = ys - (float)y0;
    float v00 = h7[x0 * 7 + y0], v01 = h7[x0 * 7 + y1];
    float v10 = h7[x1 * 7 + y0], v11 = h7[x1 * 7 + y1];
    return (1.0f - wx) * ((1.0f - wy) * v00 + wy * v01)
         + wx * ((1.0f - wy) * v10 + wy * v11);
}

__global__ __launch_bounds__(256) void k2_heatmap(const unsigned* __restrict__ heatBins,
                                                  float* __restrict__ heatOut,
                                                  unsigned long long* __restrict__ maskW) {
    __shared__ float raw[HW7];
    __shared__ float h7[HW7];
    __shared__ float s_mn, s_mx;
    const int t = threadIdx.x;
    const int b = blockIdx.x;
    const int n = b >> 3, slice = b & 7;
    if (t < HW7) raw[t] = __uint_as_float(heatBins[n * HW7 + t]);
    __syncthreads();
    if (t == 0) {
        float mn = raw[0], mx = raw[0];
        for (int i = 1; i < HW7; ++i) { float v = raw[i]; mn = fminf(mn, v); mx = fmaxf(mx, v); }
        s_mn = mn; s_mx = mx;
    }
    __syncthreads();
    if (t < HW7) h7[t] = (raw[t] - s_mn) / (s_mx - s_mn);
    __syncthreads();

    const int pbase = slice * 6272;   // 28 rows * 224
    for (int k = 0; k < 25; ++k) {
        int pl = k * 256 + t;
        if (pl < 6272) {              // last iter: waves 0,1 fully active only
            int p = pbase + pl;
            int i = p / 224, j = p % 224;
            float val = bilin7(h7, i, j);
            heatOut[(size_t)n * NPIX + p] = val;
            unsigned long long bal = __ballot(val > THRESH);
            if ((t & 63) == 0) maskW[(size_t)n * WPAD + (p >> 6)] = bal;
        }
    }
}

// =====================================================================
// K3: run-based CCL per image (one block). Exact equivalent of the
// reference min-label propagation + bincount argmax + bbox.
// =====================================================================
__device__ inline unsigned uf_find(volatile unsigned* P, unsigned x) {
    while (true) {
        unsigned p = P[x];
        if (p == x) return x;
        unsigned gp = P[p];
        if (gp == p) return p;
        P[x] = gp;      // path halving: benign race, gp < x keeps forest acyclic
        x = gp;
    }
}

__device__ inline void uf_merge(volatile unsigned* P, unsigned a, unsigned b) {
    while (true) {
        a = uf_find(P, a); b = uf_find(P, b);
        if (a == b) return;
        if (a > b) { unsigned tmp = a; a = b; b = tmp; }
        unsigned old = atomicCAS((unsigned*)&P[b], b, a);
        if (old == b) return;
        b = old;
    }
}

__global__ __launch_bounds__(256) void k3_ccl(const unsigned long long* __restrict__ maskW,
                                              float* __restrict__ coords) {
    __shared__ unsigned long long W[WPAD];
    __shared__ unsigned short runS[RCAP], runE[RCAP];
    __shared__ unsigned char nRuns[224];
    __shared__ unsigned parent[RCAP], cnt[RCAP];
    __shared__ unsigned rmin[RCAP], rmax[RCAP], cmin[RCAP], cmax[RCAP];
    __shared__ unsigned bestScore, bestRid;
    const int t = threadIdx.x;
    const int n = blockIdx.x;

    for (int i = t; i < WPAD; i += 256) W[i] = maskW[(size_t)n * WPAD + i];
    for (int i = t; i < RCAP; i += 256) {
        parent[i] = (unsigned)i; cnt[i] = 0u;
        rmin[i] = 0xFFFFFFFFu; rmax[i] = 0u; cmin[i] = 0xFFFFFFFFu; cmax[i] = 0u;
    }
    if (t == 0) { bestScore = 0u; bestRid = 0u; }
    __syncthreads();

    // ---- run extraction: one thread per row, bit-trick start/end finding
    if (t < 224) {
        const int r = t;
        const int bit0 = r * 224;
        const int w0 = bit0 >> 6, sh = bit0 & 63;
        unsigned long long rb[4];
#pragma unroll
        for (int q = 0; q < 4; ++q) {
            unsigned long long lo = W[w0 + q] >> sh;
            unsigned long long hi = sh ? (W[w0 + q + 1] << (64 - sh)) : 0ull;
            rb[q] = lo | hi;
        }
        rb[3] &= 0xFFFFFFFFull;   // keep bits 192..223 only

        unsigned long long st[4], en[4];
        unsigned long long carry = 0ull;
#pragma unroll
        for (int q = 0; q < 4; ++q) {
            unsigned long long shl = (rb[q] << 1) | carry;
            carry = rb[q] >> 63;
            st[q] = rb[q] & ~shl;                         // run starts
        }
#pragma unroll
        for (int q = 0; q < 4; ++q) {
            unsigned long long nxt = (q < 3) ? rb[q + 1] : 0ull;
            en[q] = rb[q] & ~((rb[q] >> 1) | (nxt << 63)); // run ends
        }
        int ns = 0;
#pragma unroll
        for (int q = 0; q < 4; ++q) {
            unsigned long long x = st[q];
            while (x) {
                int z = __builtin_ctzll(x); x &= x - 1;
                if (ns < MAXR) runS[r * MAXR + ns] = (unsigned short)(q * 64 + z);
                ns++;
            }
        }
        int ne = 0;
#pragma unroll
        for (int q = 0; q < 4; ++q) {
            unsigned long long x = en[q];
            while (x) {
                int z = __builtin_ctzll(x); x &= x - 1;
                if (ne < MAXR) runE[r * MAXR + ne] = (unsigned short)(q * 64 + z);
                ne++;
            }
        }
        nRuns[r] = (unsigned char)min(ns, MAXR);
    }
    __syncthreads();

    // ---- union runs overlapping (8-connectivity) with previous row
    if (t >= 1 && t < 224) {
        const int r = t;
        const int na = nRuns[r], nb = nRuns[r - 1];
        for (int k = 0; k < na; ++k) {
            int rid = r * MAXR + k;
            int s = runS[rid], e = runE[rid];
            for (int m = 0; m < nb; ++m) {
                int qid = (r - 1) * MAXR + m;
                int s2 = runS[qid], e2 = runE[qid];
                if (s2 <= e + 1 && e2 >= s - 1) uf_merge(parent, (unsigned)rid, (unsigned)qid);
            }
        }
    }
    __syncthreads();

    // ---- accumulate sizes + per-component bbox
    for (int rid = t; rid < RCAP; rid += 256) {
        int r = rid >> 3, k = rid & (MAXR - 1);
        if (k < (int)nRuns[r]) {
            int s = runS[rid], e = runE[rid];
            unsigned root = uf_find(parent, (unsigned)rid);
            atomicAdd(&cnt[root], (unsigned)(e - s + 1));
            atomicMin(&rmin[root], (unsigned)r);
            atomicMax(&rmax[root], (unsigned)r);
            atomicMin(&cmin[root], (unsigned)s);
            atomicMax(&cmax[root], (unsigned)e);
        }
    }
    __syncthreads();

    // ---- select: max count, tie -> min reference label (= min pixel index)
    for (int rid = t; rid < RCAP; rid += 256) {
        unsigned c = cnt[rid];
        if (c > 0u) {
            unsigned label = (unsigned)((rid >> 3) * 224 + (int)runS[rid]); // root = min (row,start)
            unsigned score = (c << 16) | (65535u - label);
            atomicMax(&bestScore, score);
        }
    }
    __syncthreads();
    for (int rid = t; rid < RCAP; rid += 256) {
        unsigned c = cnt[rid];
        if (c > 0u) {
            unsigned label = (unsigned)((rid >> 3) * 224 + (int)runS[rid]);
            unsigned score = (c << 16) | (65535u - label);
            if (score == bestScore) bestRid = (unsigned)rid;  // unique writer
        }
    }
    __syncthreads();

    if (t == 0) {
        int xmin, xmax, ymin, ymax;
        if (bestScore == 0u) {           // empty mask -> reference fallback
            xmin = 0; ymin = 0; xmax = 223; ymax = 223;
        } else {
            unsigned rb_ = bestRid;
            xmin = (int)rmin[rb_]; xmax = (int)rmax[rb_];
            ymin = (int)cmin[rb_]; ymax = (int)cmax[rb_];
        }
        coords[n * 4 + 0] = (float)ymin;  // torch coord order [ymin,xmin,ymax,xmax]
        coords[n * 4 + 1] = (float)xmin;
        coords[n * 4 + 2] = (float)ymax;
        coords[n * 4 + 3] = (float)xmax;
    }
}

// =====================================================================
// K4: crop + bilinear resize to 224x224 (align_corners semantics)
// =====================================================================
__global__ __launch_bounds__(256) void k4_crop(const float* __restrict__ X,
                                               const float* __restrict__ coords,
                                               float* __restrict__ out) {
#pragma clang fp contract(off)
    int id = blockIdx.x * 256 + threadIdx.x;
    if (id >= CROP_N) return;
    int n   = id / 150528;           // 3*224*224
    int rem = id % 150528;
    int p   = rem % NPIX;
    int oi  = p / 224, oj = p % 224;

    int ymin = (int)coords[n * 4 + 0];
    int xmin = (int)coords[n * 4 + 1];
    int ymax = (int)coords[n * 4 + 2];
    int xmax = (int)coords[n * 4 + 3];
    int Lx = max(xmax - xmin, 1);
    int Ly = max(ymax - ymin, 1);

    float gx = (float)oi / 223.0f;
    float gy = (float)oj / 223.0f;
    float xs = (float)xmin + gx * (float)(Lx - 1);
    float ys = (float)ymin + gy * (float)(Ly - 1);
    int x0 = (int)floorf(xs); x0 = min(max(x0, 0), 223); int x1 = min(x0 + 1, 223);
    int y0 = (int)floorf(ys); y0 = min(max(y0, 0), 223); int y1 = min(y0 + 1, 223);
    float wx = xs - (float)x0;
    float wy = ys - (float)y0;

    const float* img = X + (size_t)n * 150528 + (size_t)(rem / NPIX) * NPIX;
    float v00 = img[x0 * 224 + y0], v01 = img[x0 * 224 + y1];
    float v10 = img[x1 * 224 + y0], v11 = img[x1 * 224 + y1];
    out[id] = (1.0f - wx) * ((1.0f - wy) * v00 + wy * v01)
            + wx * ((1.0f - wy) * v10 + wy * v11);
}

// =====================================================================
extern "C" void kernel_launch(void* const* d_in, const int* in_sizes, int n_in,
                              void* d_out, int out_size, void* d_ws, size_t ws_size,
                              hipStream_t stream) {
    (void)in_sizes; (void)n_in; (void)out_size; (void)d_ws; (void)ws_size;
    const float* X = (const float*)d_in[0];   // (64,3,224,224)
    const float* F = (const float*)d_in[1];   // (64,2048,7,7)
    float* out = (float*)d_out;

    unsigned* heatBins = (unsigned*)d_out;                                   // scratch in crop region
    unsigned long long* maskW = (unsigned long long*)((char*)d_out + 16384); // scratch in crop region
    float* heatOut = out + HEAT_OFF;
    float* coords  = out + COORD_OFF;

    k0_zero   <<<dim3((SCRATCH_ULL + 255) / 256), dim3(256), 0, stream>>>((unsigned long long*)d_out);
    k1_heat   <<<dim3(512), dim3(256), 0, stream>>>(F, heatBins);
    k2_heatmap<<<dim3(512), dim3(256), 0, stream>>>(heatBins, heatOut, maskW);
    k3_ccl    <<<dim3(64),  dim3(256), 0, stream>>>(maskW, coords);
    k4_crop   <<<dim3(CROP_N / 256), dim3(256), 0, stream>>>(X, coords, out);
}

// Round 2
// 148.038 us; speedup vs baseline: 1.1214x; 1.1214x over previous
//
#include <hip/hip_runtime.h>
#include <stdint.h>

// ---------------- problem constants ----------------
#define NIMG   64
#define NCH    2048
#define HW7    49          // 7*7
#define OUTW   224
#define NPIX   50176       // 224*224
#define CROP_N 9633792     // 64*3*224*224
#define HEAT_OFF  9633792
#define COORD_OFF 12845056 // CROP_N + 64*NPIX
#define THRESH 0.7f

#define MAXR 8             // max runs kept per row (theoretical max is 4)
#define RCAP (224*MAXR)    // 1792 run slots per image
#define NWORDS 784         // 50176 bits / 64
#define WPAD   788         // padded: k3 row extraction reads +4 words (zeroed in LDS)

// scratch inside d_out's crop region (fully overwritten by k4 afterwards):
//   byte 0      : float heatPart[512*49]                (100352 B)
//   byte 131072 : unsigned long long maskW[64*788]      (403456 B) -> ends 534528
#define MASKW_BYTE_OFF 131072

// =====================================================================
// K1: heat partials. 512 blocks = 8 channel-groups x 64 images.
// Wave-per-channel: lane l (<49) accumulates max|F| for pos l in registers.
// Block (n,g) covers channels [g*256, g*256+256): wave w takes c = g*256+4i+w,
// so each block-iteration's 4 wave-loads cover 784 contiguous bytes.
// =====================================================================
__global__ __launch_bounds__(256) void k1_heat(const float* __restrict__ F,
                                               float* __restrict__ heatPart) {
    __shared__ float smax[4][64];
    const int t = threadIdx.x;
    const int b = blockIdx.x;
    const int n = b >> 3, g = b & 7;
    const int w = t >> 6, l = t & 63;
    const int lp = (l < HW7) ? l : 0;          // lanes >=49 read pos 0 (harmless, same lines)
    const float* base = F + (size_t)n * 100352 + (size_t)(g * 256 + w) * HW7 + lp;
    float vmax = 0.0f;
#pragma unroll 8
    for (int i = 0; i < 64; ++i) {
        vmax = fmaxf(vmax, fabsf(base[(size_t)i * 4 * HW7]));
    }
    smax[w][l] = vmax;
    __syncthreads();
    if (t < HW7) {
        float m = fmaxf(fmaxf(smax[0][t], smax[1][t]), fmaxf(smax[2][t], smax[3][t]));
        heatPart[b * HW7 + t] = m;
    }
}

// =====================================================================
// K2: reduce partials -> normalize -> bilinear upsample -> mask ballot.
// 512 blocks = 8 row-slices x 64 images.
// =====================================================================
__device__ inline float bilin7(const float* h7, int i, int j) {
#pragma clang fp contract(off)
    float gx = (float)i / 223.0f;
    float gy = (float)j / 223.0f;
    float xs = gx * 6.0f;
    float ys = gy * 6.0f;
    int x0 = (int)floorf(xs); x0 = min(max(x0, 0), 6); int x1 = min(x0 + 1, 6);
    int y0 = (int)floorf(ys); y0 = min(max(y0, 0), 6); int y1 = min(y0 + 1, 6);
    float wx = xs - (float)x0;
    float wy = ys - (float)y0;
    float v00 = h7[x0 * 7 + y0], v01 = h7[x0 * 7 + y1];
    float v10 = h7[x1 * 7 + y0], v11 = h7[x1 * 7 + y1];
    return (1.0f - wx) * ((1.0f - wy) * v00 + wy * v01)
         + wx * ((1.0f - wy) * v10 + wy * v11);
}

__global__ __launch_bounds__(256) void k2_heatmap(const float* __restrict__ heatPart,
                                                  float* __restrict__ heatOut,
                                                  unsigned long long* __restrict__ maskW) {
    __shared__ float raw[HW7];
    __shared__ float h7[HW7];
    __shared__ float s_mn, s_mx;
    const int t = threadIdx.x;
    const int b = blockIdx.x;
    const int n = b >> 3, slice = b & 7;
    if (t < HW7) {
        float m = heatPart[(n * 8 + 0) * HW7 + t];
#pragma unroll
        for (int g = 1; g < 8; ++g) m = fmaxf(m, heatPart[(n * 8 + g) * HW7 + t]);
        raw[t] = m;
    }
    __syncthreads();
    if (t == 0) {
        float mn = raw[0], mx = raw[0];
        for (int i = 1; i < HW7; ++i) { float v = raw[i]; mn = fminf(mn, v); mx = fmaxf(mx, v); }
        s_mn = mn; s_mx = mx;
    }
    __syncthreads();
    if (t < HW7) h7[t] = (raw[t] - s_mn) / (s_mx - s_mn);
    __syncthreads();

    const int pbase = slice * 6272;   // 28 rows * 224
#pragma unroll
    for (int k = 0; k < 25; ++k) {
        int pl = k * 256 + t;
        if (pl < 6272) {              // last iter: only waves 0,1 active
            int p = pbase + pl;
            int i = p / 224, j = p % 224;
            float val = bilin7(h7, i, j);
            heatOut[(size_t)n * NPIX + p] = val;
            unsigned long long bal = __ballot(val > THRESH);
            if ((t & 63) == 0) maskW[(size_t)n * WPAD + (p >> 6)] = bal;
        }
    }
}

// =====================================================================
// K3: run-based CCL per image (one block). Exact equivalent of the
// reference min-label propagation + bincount argmax + bbox.
// =====================================================================
__device__ inline unsigned uf_find(volatile unsigned* P, unsigned x) {
    while (true) {
        unsigned p = P[x];
        if (p == x) return x;
        unsigned gp = P[p];
        if (gp == p) return p;
        P[x] = gp;      // path halving: benign race, parent always decreases
        x = gp;
    }
}

__device__ inline void uf_merge(volatile unsigned* P, unsigned a, unsigned b) {
    while (true) {
        a = uf_find(P, a); b = uf_find(P, b);
        if (a == b) return;
        if (a > b) { unsigned tmp = a; a = b; b = tmp; }
        unsigned old = atomicCAS((unsigned*)&P[b], b, a);
        if (old == b) return;
        b = old;
    }
}

__global__ __launch_bounds__(256) void k3_ccl(const unsigned long long* __restrict__ maskW,
                                              float* __restrict__ coords) {
    __shared__ unsigned long long W[WPAD];
    __shared__ unsigned short runS[RCAP], runE[RCAP];
    __shared__ unsigned char nRuns[224];
    __shared__ unsigned parent[RCAP], cnt[RCAP];
    __shared__ unsigned rmin[RCAP], rmax[RCAP], cmin[RCAP], cmax[RCAP];
    __shared__ unsigned bestScore, bestRid;
    const int t = threadIdx.x;
    const int n = blockIdx.x;

    for (int i = t; i < NWORDS; i += 256) W[i] = maskW[(size_t)n * WPAD + i];
    if (t < WPAD - NWORDS) W[NWORDS + t] = 0ull;   // pad words: zero locally
    for (int i = t; i < RCAP; i += 256) {
        parent[i] = (unsigned)i; cnt[i] = 0u;
        rmin[i] = 0xFFFFFFFFu; rmax[i] = 0u; cmin[i] = 0xFFFFFFFFu; cmax[i] = 0u;
    }
    if (t == 0) { bestScore = 0u; bestRid = 0u; }
    __syncthreads();

    // ---- run extraction: one thread per row, bit-trick start/end finding
    if (t < 224) {
        const int r = t;
        const int bit0 = r * 224;
        const int w0 = bit0 >> 6, sh = bit0 & 63;
        unsigned long long rb[4];
#pragma unroll
        for (int q = 0; q < 4; ++q) {
            unsigned long long lo = W[w0 + q] >> sh;
            unsigned long long hi = sh ? (W[w0 + q + 1] << (64 - sh)) : 0ull;
            rb[q] = lo | hi;
        }
        rb[3] &= 0xFFFFFFFFull;   // keep bits 192..223 only

        unsigned long long st[4], en[4];
        unsigned long long carry = 0ull;
#pragma unroll
        for (int q = 0; q < 4; ++q) {
            unsigned long long shl = (rb[q] << 1) | carry;
            carry = rb[q] >> 63;
            st[q] = rb[q] & ~shl;                         // run starts
        }
#pragma unroll
        for (int q = 0; q < 4; ++q) {
            unsigned long long nxt = (q < 3) ? rb[q + 1] : 0ull;
            en[q] = rb[q] & ~((rb[q] >> 1) | (nxt << 63)); // run ends
        }
        int ns = 0;
#pragma unroll
        for (int q = 0; q < 4; ++q) {
            unsigned long long x = st[q];
            while (x) {
                int z = __builtin_ctzll(x); x &= x - 1;
                if (ns < MAXR) runS[r * MAXR + ns] = (unsigned short)(q * 64 + z);
                ns++;
            }
        }
        int ne = 0;
#pragma unroll
        for (int q = 0; q < 4; ++q) {
            unsigned long long x = en[q];
            while (x) {
                int z = __builtin_ctzll(x); x &= x - 1;
                if (ne < MAXR) runE[r * MAXR + ne] = (unsigned short)(q * 64 + z);
                ne++;
            }
        }
        nRuns[r] = (unsigned char)min(ns, MAXR);
    }
    __syncthreads();

    // ---- union runs overlapping (8-connectivity) with previous row
    if (t >= 1 && t < 224) {
        const int r = t;
        const int na = nRuns[r], nb = nRuns[r - 1];
        for (int k = 0; k < na; ++k) {
            int rid = r * MAXR + k;
            int s = runS[rid], e = runE[rid];
            for (int m = 0; m < nb; ++m) {
                int qid = (r - 1) * MAXR + m;
                int s2 = runS[qid], e2 = runE[qid];
                if (s2 <= e + 1 && e2 >= s - 1) uf_merge(parent, (unsigned)rid, (unsigned)qid);
            }
        }
    }
    __syncthreads();

    // ---- accumulate sizes + per-component bbox
    for (int rid = t; rid < RCAP; rid += 256) {
        int r = rid >> 3, k = rid & (MAXR - 1);
        if (k < (int)nRuns[r]) {
            int s = runS[rid], e = runE[rid];
            unsigned root = uf_find(parent, (unsigned)rid);
            atomicAdd(&cnt[root], (unsigned)(e - s + 1));
            atomicMin(&rmin[root], (unsigned)r);
            atomicMax(&rmax[root], (unsigned)r);
            atomicMin(&cmin[root], (unsigned)s);
            atomicMax(&cmax[root], (unsigned)e);
        }
    }
    __syncthreads();

    // ---- select: max count, tie -> min reference label (= min pixel index)
    for (int rid = t; rid < RCAP; rid += 256) {
        unsigned c = cnt[rid];
        if (c > 0u) {
            unsigned label = (unsigned)((rid >> 3) * 224 + (int)runS[rid]); // root = min (row,start)
            unsigned score = (c << 16) | (65535u - label);
            atomicMax(&bestScore, score);
        }
    }
    __syncthreads();
    for (int rid = t; rid < RCAP; rid += 256) {
        unsigned c = cnt[rid];
        if (c > 0u) {
            unsigned label = (unsigned)((rid >> 3) * 224 + (int)runS[rid]);
            unsigned score = (c << 16) | (65535u - label);
            if (score == bestScore) bestRid = (unsigned)rid;  // unique writer
        }
    }
    __syncthreads();

    if (t == 0) {
        int xmin, xmax, ymin, ymax;
        if (bestScore == 0u) {           // empty mask -> reference fallback
            xmin = 0; ymin = 0; xmax = 223; ymax = 223;
        } else {
            unsigned rb_ = bestRid;
            xmin = (int)rmin[rb_]; xmax = (int)rmax[rb_];
            ymin = (int)cmin[rb_]; ymax = (int)cmax[rb_];
        }
        coords[n * 4 + 0] = (float)ymin;  // torch coord order [ymin,xmin,ymax,xmax]
        coords[n * 4 + 1] = (float)xmin;
        coords[n * 4 + 2] = (float)ymax;
        coords[n * 4 + 3] = (float)xmax;
    }
}

// =====================================================================
// K4: crop + bilinear resize. One thread per PIXEL, all 3 channels:
// weights/index math computed once, 3 gathers + 3 coalesced stores.
// 12544 blocks = 196 per image.
// =====================================================================
__global__ __launch_bounds__(256) void k4_crop(const float* __restrict__ X,
                                               const float* __restrict__ coords,
                                               float* __restrict__ out) {
#pragma clang fp contract(off)
    const int t = threadIdx.x;
    const int b = blockIdx.x;
    const int n = b / 196;               // uniform per block -> coords loads scalarize
    const int p = (b % 196) * 256 + t;
    const int oi = p / 224, oj = p % 224;

    int ymin = (int)coords[n * 4 + 0];
    int xmin = (int)coords[n * 4 + 1];
    int ymax = (int)coords[n * 4 + 2];
    int xmax = (int)coords[n * 4 + 3];
    int Lx = max(xmax - xmin, 1);
    int Ly = max(ymax - ymin, 1);

    float gx = (float)oi / 223.0f;
    float gy = (float)oj / 223.0f;
    float xs = (float)xmin + gx * (float)(Lx - 1);
    float ys = (float)ymin + gy * (float)(Ly - 1);
    int x0 = (int)floorf(xs); x0 = min(max(x0, 0), 223); int x1 = min(x0 + 1, 223);
    int y0 = (int)floorf(ys); y0 = min(max(y0, 0), 223); int y1 = min(y0 + 1, 223);
    float wx = xs - (float)x0;
    float wy = ys - (float)y0;

    const float* img = X + (size_t)n * 150528;
    const size_t o = (size_t)n * 150528 + (size_t)p;
    const int i00 = x0 * 224 + y0, i01 = x0 * 224 + y1;
    const int i10 = x1 * 224 + y0, i11 = x1 * 224 + y1;
#pragma unroll
    for (int ch = 0; ch < 3; ++ch) {
        const float* im = img + ch * NPIX;
        float v00 = im[i00], v01 = im[i01];
        float v10 = im[i10], v11 = im[i11];
        out[o + (size_t)ch * NPIX] =
            (1.0f - wx) * ((1.0f - wy) * v00 + wy * v01)
          + wx * ((1.0f - wy) * v10 + wy * v11);
    }
}

// =====================================================================
extern "C" void kernel_launch(void* const* d_in, const int* in_sizes, int n_in,
                              void* d_out, int out_size, void* d_ws, size_t ws_size,
                              hipStream_t stream) {
    (void)in_sizes; (void)n_in; (void)out_size; (void)d_ws; (void)ws_size;
    const float* X = (const float*)d_in[0];   // (64,3,224,224)
    const float* F = (const float*)d_in[1];   // (64,2048,7,7)
    float* out = (float*)d_out;

    float* heatPart = (float*)d_out;                                          // scratch in crop region
    unsigned long long* maskW = (unsigned long long*)((char*)d_out + MASKW_BYTE_OFF);
    float* heatOut = out + HEAT_OFF;
    float* coords  = out + COORD_OFF;

    k1_heat   <<<dim3(512),   dim3(256), 0, stream>>>(F, heatPart);
    k2_heatmap<<<dim3(512),   dim3(256), 0, stream>>>(heatPart, heatOut, maskW);
    k3_ccl    <<<dim3(64),    dim3(256), 0, stream>>>(maskW, coords);
    k4_crop   <<<dim3(12544), dim3(256), 0, stream>>>(X, coords, out);
}

// Round 3
// 142.262 us; speedup vs baseline: 1.1670x; 1.0406x over previous
//
#include <hip/hip_runtime.h>
#include <stdint.h>

// ---------------- problem constants ----------------
#define NIMG   64
#define NCH    2048
#define HW7    49          // 7*7
#define OUTW   224
#define NPIX   50176       // 224*224
#define CROP_N 9633792     // 64*3*224*224
#define HEAT_OFF  9633792
#define COORD_OFF 12845056 // CROP_N + 64*NPIX
#define THRESH 0.7f

#define MAXR 8             // max runs kept per row (theoretical max is 4)
#define RCAP (224*MAXR)    // 1792 run slots per image
#define NWORDS 784         // 50176 bits / 64
#define WPAD   788         // padded: k3 row extraction reads +4 words (zeroed in LDS)

#define NGRP 16            // k1 channel groups per image (1024 blocks total)

// scratch inside d_out's crop region (fully overwritten by k4 afterwards):
//   byte 0      : float heatPart[1024*49]               (200704 B)
//   byte 262144 : unsigned long long maskW[64*788]      (403456 B) -> ends 665600
#define MASKW_BYTE_OFF 262144

// =====================================================================
// K1: heat partials. 1024 blocks = 16 channel-groups x 64 images.
// Wave-per-channel: lane l (<49) accumulates max|F| for pos l in registers.
// Block (n,g) covers channels [g*128, g*128+128): wave w takes c = g*128+4i+w,
// so each block-iteration's 4 wave-loads cover 784 contiguous bytes.
// =====================================================================
__global__ __launch_bounds__(256) void k1_heat(const float* __restrict__ F,
                                               float* __restrict__ heatPart) {
    __shared__ float smax[4][64];
    const int t = threadIdx.x;
    const int b = blockIdx.x;
    const int n = b >> 4, g = b & 15;
    const int w = t >> 6, l = t & 63;
    const int lp = (l < HW7) ? l : 0;          // lanes >=49 re-read pos 0 (same cache lines)
    const float* base = F + (size_t)n * 100352 + (size_t)(g * 128 + w) * HW7 + lp;
    float vmax = 0.0f;
#pragma unroll 8
    for (int i = 0; i < 32; ++i) {
        vmax = fmaxf(vmax, fabsf(base[(size_t)i * 4 * HW7]));
    }
    smax[w][l] = vmax;
    __syncthreads();
    if (t < HW7) {
        float m = fmaxf(fmaxf(smax[0][t], smax[1][t]), fmaxf(smax[2][t], smax[3][t]));
        heatPart[b * HW7 + t] = m;
    }
}

// =====================================================================
// K2: reduce partials -> normalize -> bilinear upsample -> mask ballot.
// 512 blocks = 8 row-slices x 64 images. Per-pixel fdivs hoisted into a
// 224-entry LDS table (identical for x and y since output is square).
// =====================================================================
__global__ __launch_bounds__(256) void k2_heatmap(const float* __restrict__ heatPart,
                                                  float* __restrict__ heatOut,
                                                  unsigned long long* __restrict__ maskW) {
#pragma clang fp contract(off)
    __shared__ float raw[HW7];
    __shared__ float h7[HW7];
    __shared__ float s_mn, s_mx;
    __shared__ float wT[OUTW];      // fractional weight per output index
    __shared__ int   i0T[OUTW];     // low tap (x0 == y0 formula)
    __shared__ int   i1T[OUTW];     // high tap
    const int t = threadIdx.x;
    const int b = blockIdx.x;
    const int n = b >> 3, slice = b & 7;

    if (t < HW7) {
        float m = heatPart[(n * NGRP + 0) * HW7 + t];
#pragma unroll
        for (int g = 1; g < NGRP; ++g) m = fmaxf(m, heatPart[(n * NGRP + g) * HW7 + t]);
        raw[t] = m;
    }
    if (t < OUTW) {
        // EXACT reference op order: g = i/223 ; s = g*6 ; floor/clip ; w = s - i0
        float gx = (float)t / 223.0f;
        float xs = gx * 6.0f;
        int x0 = (int)floorf(xs); x0 = min(max(x0, 0), 6);
        i0T[t] = x0;
        i1T[t] = min(x0 + 1, 6);
        wT[t]  = xs - (float)x0;
    }
    __syncthreads();
    if (t == 0) {
        float mn = raw[0], mx = raw[0];
        for (int i = 1; i < HW7; ++i) { float v = raw[i]; mn = fminf(mn, v); mx = fmaxf(mx, v); }
        s_mn = mn; s_mx = mx;
    }
    __syncthreads();
    if (t < HW7) h7[t] = (raw[t] - s_mn) / (s_mx - s_mn);
    __syncthreads();

    const int pbase = slice * 6272;   // 28 rows * 224
    for (int k = 0; k < 25; ++k) {
        int pl = k * 256 + t;
        if (pl < 6272) {              // last iter: only waves 0,1 active
            int p = pbase + pl;
            int i = p / 224, j = p - i * 224;
            int x0 = i0T[i], x1 = i1T[i];
            int y0 = i0T[j], y1 = i1T[j];
            float wx = wT[i], wy = wT[j];
            float v00 = h7[x0 * 7 + y0], v01 = h7[x0 * 7 + y1];
            float v10 = h7[x1 * 7 + y0], v11 = h7[x1 * 7 + y1];
            float val = (1.0f - wx) * ((1.0f - wy) * v00 + wy * v01)
                      + wx * ((1.0f - wy) * v10 + wy * v11);
            heatOut[(size_t)n * NPIX + p] = val;
            unsigned long long bal = __ballot(val > THRESH);
            if ((t & 63) == 0) maskW[(size_t)n * WPAD + (p >> 6)] = bal;
        }
    }
}

// =====================================================================
// K3: run-based CCL per image (one block). Exact equivalent of the
// reference min-label propagation + bincount argmax + bbox.
// =====================================================================
__device__ inline unsigned uf_find(volatile unsigned* P, unsigned x) {
    while (true) {
        unsigned p = P[x];
        if (p == x) return x;
        unsigned gp = P[p];
        if (gp == p) return p;
        P[x] = gp;      // path halving: benign race, parent always decreases
        x = gp;
    }
}

__device__ inline void uf_merge(volatile unsigned* P, unsigned a, unsigned b) {
    while (true) {
        a = uf_find(P, a); b = uf_find(P, b);
        if (a == b) return;
        if (a > b) { unsigned tmp = a; a = b; b = tmp; }
        unsigned old = atomicCAS((unsigned*)&P[b], b, a);
        if (old == b) return;
        b = old;
    }
}

__global__ __launch_bounds__(256) void k3_ccl(const unsigned long long* __restrict__ maskW,
                                              float* __restrict__ coords) {
    __shared__ unsigned long long W[WPAD];
    __shared__ unsigned short runS[RCAP], runE[RCAP];
    __shared__ unsigned char nRuns[224];
    __shared__ unsigned parent[RCAP], cnt[RCAP];
    __shared__ unsigned rmin[RCAP], rmax[RCAP], cmin[RCAP], cmax[RCAP];
    __shared__ unsigned bestScore, bestRid;
    const int t = threadIdx.x;
    const int n = blockIdx.x;

    for (int i = t; i < NWORDS; i += 256) W[i] = maskW[(size_t)n * WPAD + i];
    if (t < WPAD - NWORDS) W[NWORDS + t] = 0ull;   // pad words: zero locally
    for (int i = t; i < RCAP; i += 256) {
        parent[i] = (unsigned)i; cnt[i] = 0u;
        rmin[i] = 0xFFFFFFFFu; rmax[i] = 0u; cmin[i] = 0xFFFFFFFFu; cmax[i] = 0u;
    }
    if (t == 0) { bestScore = 0u; bestRid = 0u; }
    __syncthreads();

    // ---- run extraction: one thread per row, bit-trick start/end finding
    if (t < 224) {
        const int r = t;
        const int bit0 = r * 224;
        const int w0 = bit0 >> 6, sh = bit0 & 63;
        unsigned long long rb[4];
#pragma unroll
        for (int q = 0; q < 4; ++q) {
            unsigned long long lo = W[w0 + q] >> sh;
            unsigned long long hi = sh ? (W[w0 + q + 1] << (64 - sh)) : 0ull;
            rb[q] = lo | hi;
        }
        rb[3] &= 0xFFFFFFFFull;   // keep bits 192..223 only

        unsigned long long st[4], en[4];
        unsigned long long carry = 0ull;
#pragma unroll
        for (int q = 0; q < 4; ++q) {
            unsigned long long shl = (rb[q] << 1) | carry;
            carry = rb[q] >> 63;
            st[q] = rb[q] & ~shl;                         // run starts
        }
#pragma unroll
        for (int q = 0; q < 4; ++q) {
            unsigned long long nxt = (q < 3) ? rb[q + 1] : 0ull;
            en[q] = rb[q] & ~((rb[q] >> 1) | (nxt << 63)); // run ends
        }
        int ns = 0;
#pragma unroll
        for (int q = 0; q < 4; ++q) {
            unsigned long long x = st[q];
            while (x) {
                int z = __builtin_ctzll(x); x &= x - 1;
                if (ns < MAXR) runS[r * MAXR + ns] = (unsigned short)(q * 64 + z);
                ns++;
            }
        }
        int ne = 0;
#pragma unroll
        for (int q = 0; q < 4; ++q) {
            unsigned long long x = en[q];
            while (x) {
                int z = __builtin_ctzll(x); x &= x - 1;
                if (ne < MAXR) runE[r * MAXR + ne] = (unsigned short)(q * 64 + z);
                ne++;
            }
        }
        nRuns[r] = (unsigned char)min(ns, MAXR);
    }
    __syncthreads();

    // ---- union runs overlapping (8-connectivity) with previous row
    if (t >= 1 && t < 224) {
        const int r = t;
        const int na = nRuns[r], nb = nRuns[r - 1];
        for (int k = 0; k < na; ++k) {
            int rid = r * MAXR + k;
            int s = runS[rid], e = runE[rid];
            for (int m = 0; m < nb; ++m) {
                int qid = (r - 1) * MAXR + m;
                int s2 = runS[qid], e2 = runE[qid];
                if (s2 <= e + 1 && e2 >= s - 1) uf_merge(parent, (unsigned)rid, (unsigned)qid);
            }
        }
    }
    __syncthreads();

    // ---- accumulate sizes + per-component bbox
    for (int rid = t; rid < RCAP; rid += 256) {
        int r = rid >> 3, k = rid & (MAXR - 1);
        if (k < (int)nRuns[r]) {
            int s = runS[rid], e = runE[rid];
            unsigned root = uf_find(parent, (unsigned)rid);
            atomicAdd(&cnt[root], (unsigned)(e - s + 1));
            atomicMin(&rmin[root], (unsigned)r);
            atomicMax(&rmax[root], (unsigned)r);
            atomicMin(&cmin[root], (unsigned)s);
            atomicMax(&cmax[root], (unsigned)e);
        }
    }
    __syncthreads();

    // ---- select: max count, tie -> min reference label (= min pixel index)
    for (int rid = t; rid < RCAP; rid += 256) {
        unsigned c = cnt[rid];
        if (c > 0u) {
            unsigned label = (unsigned)((rid >> 3) * 224 + (int)runS[rid]); // root = min (row,start)
            unsigned score = (c << 16) | (65535u - label);
            atomicMax(&bestScore, score);
        }
    }
    __syncthreads();
    for (int rid = t; rid < RCAP; rid += 256) {
        unsigned c = cnt[rid];
        if (c > 0u) {
            unsigned label = (unsigned)((rid >> 3) * 224 + (int)runS[rid]);
            unsigned score = (c << 16) | (65535u - label);
            if (score == bestScore) bestRid = (unsigned)rid;  // unique writer
        }
    }
    __syncthreads();

    if (t == 0) {
        int xmin, xmax, ymin, ymax;
        if (bestScore == 0u) {           // empty mask -> reference fallback
            xmin = 0; ymin = 0; xmax = 223; ymax = 223;
        } else {
            unsigned rb_ = bestRid;
            xmin = (int)rmin[rb_]; xmax = (int)rmax[rb_];
            ymin = (int)cmin[rb_]; ymax = (int)cmax[rb_];
        }
        coords[n * 4 + 0] = (float)ymin;  // torch coord order [ymin,xmin,ymax,xmax]
        coords[n * 4 + 1] = (float)xmin;
        coords[n * 4 + 2] = (float)ymax;
        coords[n * 4 + 3] = (float)xmax;
    }
}

// =====================================================================
// K4: crop + bilinear resize. One thread per PIXEL, all 3 channels:
// weights/index math computed once, 3 gathers + 3 coalesced stores.
// 12544 blocks = 196 per image. Memory-bound (~77 MB) — left lean.
// =====================================================================
__global__ __launch_bounds__(256) void k4_crop(const float* __restrict__ X,
                                               const float* __restrict__ coords,
                                               float* __restrict__ out) {
#pragma clang fp contract(off)
    const int t = threadIdx.x;
    const int b = blockIdx.x;
    const int n = b / 196;               // uniform per block -> coords loads scalarize
    const int p = (b % 196) * 256 + t;
    const int oi = p / 224, oj = p % 224;

    int ymin = (int)coords[n * 4 + 0];
    int xmin = (int)coords[n * 4 + 1];
    int ymax = (int)coords[n * 4 + 2];
    int xmax = (int)coords[n * 4 + 3];
    int Lx = max(xmax - xmin, 1);
    int Ly = max(ymax - ymin, 1);

    float gx = (float)oi / 223.0f;
    float gy = (float)oj / 223.0f;
    float xs = (float)xmin + gx * (float)(Lx - 1);
    float ys = (float)ymin + gy * (float)(Ly - 1);
    int x0 = (int)floorf(xs); x0 = min(max(x0, 0), 223); int x1 = min(x0 + 1, 223);
    int y0 = (int)floorf(ys); y0 = min(max(y0, 0), 223); int y1 = min(y0 + 1, 223);
    float wx = xs - (float)x0;
    float wy = ys - (float)y0;

    const float* img = X + (size_t)n * 150528;
    const size_t o = (size_t)n * 150528 + (size_t)p;
    const int i00 = x0 * 224 + y0, i01 = x0 * 224 + y1;
    const int i10 = x1 * 224 + y0, i11 = x1 * 224 + y1;
#pragma unroll
    for (int ch = 0; ch < 3; ++ch) {
        const float* im = img + ch * NPIX;
        float v00 = im[i00], v01 = im[i01];
        float v10 = im[i10], v11 = im[i11];
        out[o + (size_t)ch * NPIX] =
            (1.0f - wx) * ((1.0f - wy) * v00 + wy * v01)
          + wx * ((1.0f - wy) * v10 + wy * v11);
    }
}

// =====================================================================
extern "C" void kernel_launch(void* const* d_in, const int* in_sizes, int n_in,
                              void* d_out, int out_size, void* d_ws, size_t ws_size,
                              hipStream_t stream) {
    (void)in_sizes; (void)n_in; (void)out_size; (void)d_ws; (void)ws_size;
    const float* X = (const float*)d_in[0];   // (64,3,224,224)
    const float* F = (const float*)d_in[1];   // (64,2048,7,7)
    float* out = (float*)d_out;

    float* heatPart = (float*)d_out;                                          // scratch in crop region
    unsigned long long* maskW = (unsigned long long*)((char*)d_out + MASKW_BYTE_OFF);
    float* heatOut = out + HEAT_OFF;
    float* coords  = out + COORD_OFF;

    k1_heat   <<<dim3(1024),  dim3(256), 0, stream>>>(F, heatPart);
    k2_heatmap<<<dim3(512),   dim3(256), 0, stream>>>(heatPart, heatOut, maskW);
    k3_ccl    <<<dim3(64),    dim3(256), 0, stream>>>(maskW, coords);
    k4_crop   <<<dim3(12544), dim3(256), 0, stream>>>(X, coords, out);
}